// Round 5
// baseline (223.629 us; speedup 1.0000x reference)
//
#include <hip/hip_runtime.h>
#include <stdint.h>

// Problem dims (LSTMCell: B=4096, IN=1024, H=1024)
#define Bn 4096
#define INn 1024
#define Hn 1024
#define Kn 2048   // IN + H
#define Nn 4096   // 4*H

// GEMM tile: 128 batch rows x 256 W-rows (= 4 gates x 64 h), BK=64
#define BM 128
#define BN 256
#define BK 64
#define KT (Kn / BK)   // 32 K-tiles

typedef __attribute__((ext_vector_type(8))) short bf16x8;
typedef __attribute__((ext_vector_type(4))) float f32x4;
typedef __attribute__((ext_vector_type(4))) unsigned short us4;

// ---------- helpers ----------
__device__ __forceinline__ unsigned short f2bf(float f) {
  uint32_t u = __float_as_uint(f);
  u += 0x7fffu + ((u >> 16) & 1u);
  return (unsigned short)(u >> 16);
}

typedef __attribute__((address_space(3))) unsigned int as3_uint;
typedef const __attribute__((address_space(1))) unsigned int as1_uint;

__device__ __forceinline__ void gload16(const unsigned short* g, unsigned short* l) {
  // async global->LDS, 16B/lane; LDS dest is wave-uniform base + lane*16 (verified layout below)
  __builtin_amdgcn_global_load_lds((as1_uint*)g, (as3_uint*)l, 16, 0, 0);
}

__device__ __forceinline__ float sigm(float x) { return 1.f / (1.f + __expf(-x)); }
__device__ __forceinline__ float tanh_fast(float x) { return 2.f / (1.f + __expf(-2.f * x)) - 1.f; }

// ---------- kernel 1: fused f32->bf16 pack (x | h_prev -> A, W -> Wbf), single launch ----------
__global__ void pack_all(const float* __restrict__ x, const float* __restrict__ h,
                         const float* __restrict__ W,
                         unsigned short* __restrict__ Abf, unsigned short* __restrict__ Wbf) {
  const long XQ = (long)Bn * INn / 4;          // 1M quads
  const long WQ = (long)Nn * Kn / 4;           // 2M quads
  const long total = XQ + XQ + WQ;
  const long stride = (long)gridDim.x * blockDim.x;
  for (long q = (long)blockIdx.x * blockDim.x + threadIdx.x; q < total; q += stride) {
    float4 v;
    unsigned short* dst;
    if (q < XQ) {
      long e = q << 2;
      v = *(const float4*)(x + e);
      dst = Abf + ((long)(e >> 10) * Kn) + (e & 1023);
    } else if (q < 2 * XQ) {
      long e = (q - XQ) << 2;
      v = *(const float4*)(h + e);
      dst = Abf + ((long)(e >> 10) * Kn) + INn + (e & 1023);
    } else {
      long e = (q - 2 * XQ) << 2;
      v = *(const float4*)(W + e);
      dst = Wbf + e;
    }
    us4 o;
    o.x = f2bf(v.x); o.y = f2bf(v.y); o.z = f2bf(v.z); o.w = f2bf(v.w);
    *(us4*)dst = o;
  }
}

// ---------- kernel 2: fused GEMM + LSTM epilogue, phase-split counted-vmcnt schedule ----------
// A: [B][K] bf16.  Wbf: [4H][K] bf16.  Block = 128 batch x (4 gates x 64 h).
// 8 waves: wr = wid>>2 (batch 64-half), wc = wid&3 (h 16-group). Fragment n = gate.
// LDS: 3 rotating buffers (stage t+2 while computing t -> never the buffer being read:
//   (t+2)%3 == (t-1)%3, whose reads completed before the boundary barrier of t).
// T2 swizzle (both-sides, rule #21): LDS[row][c] = global[row][c ^ (row&7)] via
// pre-swizzled GLOBAL source (LDS dest stays wave-uniform base + lane*16) +
// inverse-swizzled ds_read offsets. 16-lane groups then cover all 32 banks 2-way (free).
#define STAGE_A(t_, b_) do {                                                     \
    const int k0_ = (t_) * BK;                                                   \
    gload16(Ag + (long)(brow + srow) * Kn + k0_ + scol,                          \
            &bufA[b_][srow * BK + sc8 * 8]);                                     \
    gload16(Ag + (long)(brow + 64 + srow) * Kn + k0_ + scol,                     \
            &bufA[b_][(64 + srow) * BK + sc8 * 8]);                              \
  } while (0)
#define STAGE_B(t_, b_, j_) do {                                                 \
    const int k0_ = (t_) * BK;                                                   \
    const int rb_ = (j_) * 64 + srow;                                            \
    const int grow_ = ((rb_ >> 4) & 3) * Hn + h0 + ((rb_ >> 6) << 4) + (rb_ & 15);\
    gload16(Wg + (long)grow_ * Kn + k0_ + scol,                                  \
            &bufB[b_][rb_ * BK + sc8 * 8]);                                      \
  } while (0)
#define FENCE() do { asm volatile("" ::: "memory"); __builtin_amdgcn_sched_barrier(0); } while (0)

__global__ void __launch_bounds__(512, 2)
lstm_gemm_fused(const unsigned short* __restrict__ Ag,
                const unsigned short* __restrict__ Wg,
                const float* __restrict__ c_prev,
                const float* __restrict__ bias,
                float* __restrict__ out) {
  __shared__ unsigned short bufA[3][BM * BK];   // 3 x 16 KB
  __shared__ unsigned short bufB[3][BN * BK];   // 3 x 32 KB  (total 144 KB)

  const int tid = threadIdx.x;
  const int lane = tid & 63;
  const int wid = tid >> 6;
  const int wr = wid >> 2;            // 0..1 : batch half
  const int wc = wid & 3;             // 0..3 : h 16-group
  const int brow = blockIdx.y * BM;
  const int h0 = blockIdx.x * 64;

  // staging thread map: 512 thr x 16B = 8KB = 64 rows x 64 cols per issue.
  // Per wave: srow = wid*8 + (lane>>3), sc8 = lane&7 -> LDS byte off = wid*1024 + lane*16. (uniform+lane*16 ✓)
  const int srow = tid >> 3;                      // 0..63
  const int sc8 = tid & 7;                        // dest chunk 0..7
  const int scol = ((sc8 ^ (srow & 7)) * 8);      // pre-swizzled source col (elems)

  // fragment read offsets (inverse swizzle): logical chunk c -> LDS chunk c ^ (row&7);
  // row&7 == l15&7 for all fragment rows (wr*64, wc*64, m*16, n*16 are mult. of 8)
  const int l15 = lane & 15;
  const int s7 = l15 & 7;
  const int cA = lane >> 4;                       // 0..3
  const int aOff0 = (wr * 64 + l15) * BK + ((cA) ^ s7) * 8;
  const int aOff1 = (wr * 64 + l15) * BK + ((cA + 4) ^ s7) * 8;
  const int bOff0 = (wc * 64 + l15) * BK + ((cA) ^ s7) * 8;
  const int bOff1 = (wc * 64 + l15) * BK + ((cA + 4) ^ s7) * 8;

  f32x4 acc[4][4] = {};   // acc[m][n]: m = batch frag (16 rows), n = GATE

  // prologue: stage tiles 0,1 (6 loads each per wave -> 12 outstanding)
  STAGE_A(0, 0); STAGE_B(0, 0, 0); STAGE_B(0, 0, 1); STAGE_B(0, 0, 2); STAGE_B(0, 0, 3);
  STAGE_A(1, 1); STAGE_B(1, 1, 0); STAGE_B(1, 1, 1); STAGE_B(1, 1, 2); STAGE_B(1, 1, 3);

  for (int t = 0; t < KT; ++t) {
    const int bi = t % 3;
    const int sb = (t + 2) % 3;
    const bool st = (t + 2) < KT;
    // boundary: drain own tile-t loads (counted vmcnt, never 0 until the last tile),
    // then barrier -> all waves' tile-t loads have landed.
    if (t < KT - 1) asm volatile("s_waitcnt vmcnt(6)" ::: "memory");
    else            asm volatile("s_waitcnt vmcnt(0)" ::: "memory");
    __builtin_amdgcn_s_barrier();
    FENCE();

    const unsigned short* As = bufA[bi];
    const unsigned short* Bs = bufB[bi];
    bf16x8 bfr[4][2], af[2][2];

    // ---- phase 0: read B frags (8) + A quad0 (4), stage 3 loads, MFMA quad0 ----
#pragma unroll
    for (int n = 0; n < 4; ++n) {
      bfr[n][0] = *(const bf16x8*)&Bs[bOff0 + n * 16 * BK];
      bfr[n][1] = *(const bf16x8*)&Bs[bOff1 + n * 16 * BK];
    }
#pragma unroll
    for (int m = 0; m < 2; ++m) {
      af[m][0] = *(const bf16x8*)&As[aOff0 + m * 16 * BK];
      af[m][1] = *(const bf16x8*)&As[aOff1 + m * 16 * BK];
    }
    if (st) { STAGE_A(t + 2, sb); STAGE_B(t + 2, sb, 0); }
    __builtin_amdgcn_s_barrier();
    FENCE();
    __builtin_amdgcn_s_setprio(1);
#pragma unroll
    for (int m = 0; m < 2; ++m)
#pragma unroll
      for (int n = 0; n < 4; ++n) {
        acc[m][n] = __builtin_amdgcn_mfma_f32_16x16x32_bf16(af[m][0], bfr[n][0], acc[m][n], 0, 0, 0);
        acc[m][n] = __builtin_amdgcn_mfma_f32_16x16x32_bf16(af[m][1], bfr[n][1], acc[m][n], 0, 0, 0);
      }
    __builtin_amdgcn_s_setprio(0);
    FENCE();
    __builtin_amdgcn_s_barrier();
    FENCE();

    // ---- phase 1: read A quad1 (4), stage 3 loads, MFMA quad1 ----
#pragma unroll
    for (int m = 0; m < 2; ++m) {
      af[m][0] = *(const bf16x8*)&As[aOff0 + (m + 2) * 16 * BK];
      af[m][1] = *(const bf16x8*)&As[aOff1 + (m + 2) * 16 * BK];
    }
    if (st) { STAGE_B(t + 2, sb, 1); STAGE_B(t + 2, sb, 2); STAGE_B(t + 2, sb, 3); }
    __builtin_amdgcn_s_barrier();
    FENCE();
    __builtin_amdgcn_s_setprio(1);
#pragma unroll
    for (int m = 0; m < 2; ++m)
#pragma unroll
      for (int n = 0; n < 4; ++n) {
        acc[m + 2][n] = __builtin_amdgcn_mfma_f32_16x16x32_bf16(af[m][0], bfr[n][0], acc[m + 2][n], 0, 0, 0);
        acc[m + 2][n] = __builtin_amdgcn_mfma_f32_16x16x32_bf16(af[m][1], bfr[n][1], acc[m + 2][n], 0, 0, 0);
      }
    __builtin_amdgcn_s_setprio(0);
    FENCE();
    // closing barrier = next iteration's boundary barrier
  }

  // ---- fused LSTM epilogue, in-register ----
  // C/D layout (verified m89/m91): col = lane&15 (h), row = (lane>>4)*4 + j
  const int hcol = h0 + wc * 16 + l15;
  const float bf_ = bias[hcol];
  const float bi_ = bias[Hn + hcol];
  const float bg_ = bias[2 * Hn + hcol];
  const float bo_ = bias[3 * Hn + hcol];
  const int rbase = brow + wr * 64 + ((lane >> 4) << 2);
  const long BH = (long)Bn * Hn;
#pragma unroll
  for (int m = 0; m < 4; ++m) {
#pragma unroll
    for (int j = 0; j < 4; ++j) {
      const long r = rbase + m * 16 + j;
      const float f = sigm(acc[m][0][j] + bf_);
      const float i_ = sigm(acc[m][1][j] + bi_);
      const float g = tanh_fast(acc[m][2][j] + bg_);
      const float o = sigm(acc[m][3][j] + bo_);
      const float cp = c_prev[r * Hn + hcol];
      const float ct = f * cp + i_ * g;
      out[r * Hn + hcol] = o * tanh_fast(ct);   // h_t
      out[BH + r * Hn + hcol] = ct;             // c_t
    }
  }
}

// ---------- launch ----------
extern "C" void kernel_launch(void* const* d_in, const int* in_sizes, int n_in,
                              void* d_out, int out_size, void* d_ws, size_t ws_size,
                              hipStream_t stream) {
  const float* x      = (const float*)d_in[0];
  const float* h_prev = (const float*)d_in[1];
  const float* c_prev = (const float*)d_in[2];
  const float* W      = (const float*)d_in[3];
  const float* bias   = (const float*)d_in[4];
  float* out = (float*)d_out;

  // workspace: A_bf16 (B x K, 16MB) | W_bf16 (4H x K, 16MB)
  unsigned short* Abf = (unsigned short*)d_ws;
  unsigned short* Wbf = Abf + (long)Bn * Kn;

  pack_all<<<2048, 256, 0, stream>>>(x, h_prev, W, Abf, Wbf);

  // grid: x = h tiles (1024/64 = 16), y = batch tiles (4096/128 = 32)
  dim3 grid(Hn / 64, Bn / BM);
  lstm_gemm_fused<<<grid, 512, 0, stream>>>(Abf, Wbf, c_prev, bias, out);
}

// Round 8
// 215.485 us; speedup vs baseline: 1.0378x; 1.0378x over previous
//
#include <hip/hip_runtime.h>
#include <stdint.h>

// Problem dims (LSTMCell: B=4096, IN=1024, H=1024)
#define Bn 4096
#define INn 1024
#define Hn 1024
#define Kn 2048   // IN + H
#define Nn 4096   // 4*H

// GEMM tile: 128 batch rows x 256 W-rows (= 4 gates x 64 h), BK=64
#define BM 128
#define BN 256
#define BK 64
#define KT (Kn / BK)   // 32 K-tiles

typedef __attribute__((ext_vector_type(8))) short bf16x8;
typedef __attribute__((ext_vector_type(4))) float f32x4;
typedef __attribute__((ext_vector_type(4))) unsigned short us4;

// ---------- helpers ----------
__device__ __forceinline__ unsigned short f2bf(float f) {
  uint32_t u = __float_as_uint(f);
  u += 0x7fffu + ((u >> 16) & 1u);
  return (unsigned short)(u >> 16);
}

typedef __attribute__((address_space(3))) unsigned int as3_uint;
typedef const __attribute__((address_space(1))) unsigned int as1_uint;

__device__ __forceinline__ void gload16(const unsigned short* g, unsigned short* l) {
  // async global->LDS, 16B/lane; LDS dest is wave-uniform base + lane*16
  __builtin_amdgcn_global_load_lds((as1_uint*)g, (as3_uint*)l, 16, 0, 0);
}

__device__ __forceinline__ float sigm(float x) { return 1.f / (1.f + __expf(-x)); }
__device__ __forceinline__ float tanh_fast(float x) { return 2.f / (1.f + __expf(-2.f * x)) - 1.f; }

// ---------- kernel 1: fused f32->bf16 pack (x | h_prev -> A, W -> Wbf) ----------
__global__ void pack_all(const float* __restrict__ x, const float* __restrict__ h,
                         const float* __restrict__ W,
                         unsigned short* __restrict__ Abf, unsigned short* __restrict__ Wbf) {
  const long XQ = (long)Bn * INn / 4;
  const long WQ = (long)Nn * Kn / 4;
  const long total = XQ + XQ + WQ;
  const long stride = (long)gridDim.x * blockDim.x;
  for (long q = (long)blockIdx.x * blockDim.x + threadIdx.x; q < total; q += stride) {
    float4 v;
    unsigned short* dst;
    if (q < XQ) {
      long e = q << 2;
      v = *(const float4*)(x + e);
      dst = Abf + ((long)(e >> 10) * Kn) + (e & 1023);
    } else if (q < 2 * XQ) {
      long e = (q - XQ) << 2;
      v = *(const float4*)(h + e);
      dst = Abf + ((long)(e >> 10) * Kn) + INn + (e & 1023);
    } else {
      long e = (q - 2 * XQ) << 2;
      v = *(const float4*)(W + e);
      dst = Wbf + e;
    }
    us4 o;
    o.x = f2bf(v.x); o.y = f2bf(v.y); o.z = f2bf(v.z); o.w = f2bf(v.w);
    *(us4*)dst = o;
  }
}

// ---------- kernel 2: fused GEMM + LSTM epilogue ----------
// ONE barrier + ONE counted vmcnt per K-tile (R5 post-mortem: 4 barriers/tile at
// 1 block/CU was the regression — barrier stalls had no co-resident block to hide them).
// 3 rotating LDS buffers: stage t+2 into buf (t+2)%3 == (t-1)%3, whose reads were
// drained (per-wave lgkmcnt before tile t-1 MFMAs) before the boundary barrier of t.
// T2 swizzle (verified R5: conflicts 2.5e7 -> 0): LDS[row][c] = global[row][c^(row&7)]
// via pre-swizzled GLOBAL source + inverse-swizzled ds_read offsets.
#define STAGE_A(t_, b_) do {                                                     \
    const int k0_ = (t_) * BK;                                                   \
    gload16(Ag + (long)(brow + srow) * Kn + k0_ + scol,                          \
            &bufA[b_][srow * BK + sc8 * 8]);                                     \
    gload16(Ag + (long)(brow + 64 + srow) * Kn + k0_ + scol,                     \
            &bufA[b_][(64 + srow) * BK + sc8 * 8]);                              \
  } while (0)
#define STAGE_B(t_, b_, j_) do {                                                 \
    const int k0_ = (t_) * BK;                                                   \
    const int rb_ = (j_) * 64 + srow;                                            \
    const int grow_ = ((rb_ >> 4) & 3) * Hn + h0 + ((rb_ >> 6) << 4) + (rb_ & 15);\
    gload16(Wg + (long)grow_ * Kn + k0_ + scol,                                  \
            &bufB[b_][rb_ * BK + sc8 * 8]);                                      \
  } while (0)
#define FENCE() do { asm volatile("" ::: "memory"); __builtin_amdgcn_sched_barrier(0); } while (0)

__global__ void __launch_bounds__(512, 2)
lstm_gemm_fused(const unsigned short* __restrict__ Ag,
                const unsigned short* __restrict__ Wg,
                const float* __restrict__ c_prev,
                const float* __restrict__ bias,
                float* __restrict__ out) {
  __shared__ unsigned short bufA[3][BM * BK];   // 3 x 16 KB
  __shared__ unsigned short bufB[3][BN * BK];   // 3 x 32 KB  (total 144 KB)

  const int tid = threadIdx.x;
  const int lane = tid & 63;
  const int wid = tid >> 6;
  const int wr = wid >> 2;            // 0..1 : batch half
  const int wc = wid & 3;             // 0..3 : h 16-group
  const int brow = blockIdx.y * BM;
  const int h0 = blockIdx.x * 64;

  // staging map: 512 thr x 16B = 8KB = 64 rows x 64 cols per issue
  const int srow = tid >> 3;                      // 0..63
  const int sc8 = tid & 7;                        // dest chunk 0..7
  const int scol = ((sc8 ^ (srow & 7)) * 8);      // pre-swizzled source col (elems)

  // fragment read offsets (inverse swizzle): chunk c -> c ^ (row&7), row&7 == l15&7
  const int l15 = lane & 15;
  const int s7 = l15 & 7;
  const int cA = lane >> 4;                       // 0..3
  const int aOff0 = (wr * 64 + l15) * BK + ((cA) ^ s7) * 8;
  const int aOff1 = (wr * 64 + l15) * BK + ((cA + 4) ^ s7) * 8;
  const int bOff0 = (wc * 64 + l15) * BK + ((cA) ^ s7) * 8;
  const int bOff1 = (wc * 64 + l15) * BK + ((cA + 4) ^ s7) * 8;

  f32x4 acc[4][4] = {};   // acc[m][n]: m = batch frag, n = GATE

  // prologue: stage tiles 0,1 (6 gloads each per wave -> 12 outstanding)
  STAGE_A(0, 0); STAGE_B(0, 0, 0); STAGE_B(0, 0, 1); STAGE_B(0, 0, 2); STAGE_B(0, 0, 3);
  STAGE_A(1, 1); STAGE_B(1, 1, 0); STAGE_B(1, 1, 1); STAGE_B(1, 1, 2); STAGE_B(1, 1, 3);

  for (int t = 0; t < KT; ++t) {
    const int bi = t % 3;
    const int sb = (t + 2) % 3;
    // boundary: drain own tile-t loads (oldest 6; counted, never 0 until last tile)
    if (t < KT - 1) asm volatile("s_waitcnt vmcnt(6)" ::: "memory");
    else            asm volatile("s_waitcnt vmcnt(0)" ::: "memory");
    __builtin_amdgcn_s_barrier();
    FENCE();

    // issue-early: stage tile t+2 (HBM latency hides under ds_read + MFMA below)
    if (t + 2 < KT) {
      STAGE_A(t + 2, sb);
      STAGE_B(t + 2, sb, 0); STAGE_B(t + 2, sb, 1);
      STAGE_B(t + 2, sb, 2); STAGE_B(t + 2, sb, 3);
    }

    const unsigned short* As = bufA[bi];
    const unsigned short* Bs = bufB[bi];
    bf16x8 af[4][2], bfr[4][2];
#pragma unroll
    for (int n = 0; n < 4; ++n) {
      bfr[n][0] = *(const bf16x8*)&Bs[bOff0 + n * 16 * BK];
      bfr[n][1] = *(const bf16x8*)&Bs[bOff1 + n * 16 * BK];
    }
#pragma unroll
    for (int m = 0; m < 4; ++m) {
      af[m][0] = *(const bf16x8*)&As[aOff0 + m * 16 * BK];
      af[m][1] = *(const bf16x8*)&As[aOff1 + m * 16 * BK];
    }
    // full 32-MFMA cluster; compiler inserts the ds_read lgkmcnt waits
    __builtin_amdgcn_s_setprio(1);
#pragma unroll
    for (int m = 0; m < 4; ++m)
#pragma unroll
      for (int n = 0; n < 4; ++n) {
        acc[m][n] = __builtin_amdgcn_mfma_f32_16x16x32_bf16(af[m][0], bfr[n][0], acc[m][n], 0, 0, 0);
        acc[m][n] = __builtin_amdgcn_mfma_f32_16x16x32_bf16(af[m][1], bfr[n][1], acc[m][n], 0, 0, 0);
      }
    __builtin_amdgcn_s_setprio(0);
    FENCE();
    // next iteration's boundary barrier closes the tile
  }

  // ---- fused LSTM epilogue, in-register ----
  // C/D layout (verified m89/m91): col = lane&15 (h), row = (lane>>4)*4 + j
  const int hcol = h0 + wc * 16 + l15;
  const float bf_ = bias[hcol];
  const float bi_ = bias[Hn + hcol];
  const float bg_ = bias[2 * Hn + hcol];
  const float bo_ = bias[3 * Hn + hcol];
  const int rbase = brow + wr * 64 + ((lane >> 4) << 2);
  const long BH = (long)Bn * Hn;
#pragma unroll
  for (int m = 0; m < 4; ++m) {
#pragma unroll
    for (int j = 0; j < 4; ++j) {
      const long r = rbase + m * 16 + j;
      const float f = sigm(acc[m][0][j] + bf_);
      const float i_ = sigm(acc[m][1][j] + bi_);
      const float g = tanh_fast(acc[m][2][j] + bg_);
      const float o = sigm(acc[m][3][j] + bo_);
      const float cp = c_prev[r * Hn + hcol];
      const float ct = f * cp + i_ * g;
      out[r * Hn + hcol] = o * tanh_fast(ct);   // h_t
      out[BH + r * Hn + hcol] = ct;             // c_t
    }
  }
}

// ---------- launch ----------
extern "C" void kernel_launch(void* const* d_in, const int* in_sizes, int n_in,
                              void* d_out, int out_size, void* d_ws, size_t ws_size,
                              hipStream_t stream) {
  const float* x      = (const float*)d_in[0];
  const float* h_prev = (const float*)d_in[1];
  const float* c_prev = (const float*)d_in[2];
  const float* W      = (const float*)d_in[3];
  const float* bias   = (const float*)d_in[4];
  float* out = (float*)d_out;

  // workspace: A_bf16 (B x K, 16MB) | W_bf16 (4H x K, 16MB)
  unsigned short* Abf = (unsigned short*)d_ws;
  unsigned short* Wbf = Abf + (long)Bn * Kn;

  pack_all<<<2048, 256, 0, stream>>>(x, h_prev, W, Abf, Wbf);

  // grid: x = h tiles (1024/64 = 16), y = batch tiles (4096/128 = 32)
  dim3 grid(Hn / 64, Bn / BM);
  lstm_gemm_fused<<<grid, 512, 0, stream>>>(Abf, Wbf, c_prev, bias, out);
}

// Round 9
// 202.180 us; speedup vs baseline: 1.1061x; 1.0658x over previous
//
#include <hip/hip_runtime.h>
#include <stdint.h>

// Problem dims (LSTMCell: B=4096, IN=1024, H=1024)
#define Bn 4096
#define INn 1024
#define Hn 1024
#define Kn 2048   // IN + H
#define Nn 4096   // 4*H

// GEMM tile: 256 batch rows x 256 W-rows (= 4 gates x 64 h), BK=64.
// 8 waves of 64x128 output each -> 42.7 FLOP per LDS byte (R8 post-mortem:
// 64x64/wave = 32 FLOP/B was LDS-pipe-bound; need >=40 to feed MFMA).
#define BM 256
#define BN 256
#define BK 64
#define KT (Kn / BK)   // 32 K-tiles

typedef __attribute__((ext_vector_type(8))) short bf16x8;
typedef __attribute__((ext_vector_type(4))) float f32x4;
typedef __attribute__((ext_vector_type(4))) unsigned short us4;

// ---------- helpers ----------
__device__ __forceinline__ unsigned short f2bf(float f) {
  uint32_t u = __float_as_uint(f);
  u += 0x7fffu + ((u >> 16) & 1u);
  return (unsigned short)(u >> 16);
}

typedef __attribute__((address_space(3))) unsigned int as3_uint;
typedef const __attribute__((address_space(1))) unsigned int as1_uint;

__device__ __forceinline__ void gload16(const unsigned short* g, unsigned short* l) {
  // async global->LDS, 16B/lane; LDS dest is wave-uniform base + lane*16
  __builtin_amdgcn_global_load_lds((as1_uint*)g, (as3_uint*)l, 16, 0, 0);
}

__device__ __forceinline__ float sigm(float x) { return 1.f / (1.f + __expf(-x)); }
__device__ __forceinline__ float tanh_fast(float x) { return 2.f / (1.f + __expf(-2.f * x)) - 1.f; }

// ---------- kernel 1: fused f32->bf16 pack (x | h_prev -> A, W -> Wbf) ----------
__global__ void pack_all(const float* __restrict__ x, const float* __restrict__ h,
                         const float* __restrict__ W,
                         unsigned short* __restrict__ Abf, unsigned short* __restrict__ Wbf) {
  const long XQ = (long)Bn * INn / 4;
  const long WQ = (long)Nn * Kn / 4;
  const long total = XQ + XQ + WQ;
  const long stride = (long)gridDim.x * blockDim.x;
  for (long q = (long)blockIdx.x * blockDim.x + threadIdx.x; q < total; q += stride) {
    float4 v;
    unsigned short* dst;
    if (q < XQ) {
      long e = q << 2;
      v = *(const float4*)(x + e);
      dst = Abf + ((long)(e >> 10) * Kn) + (e & 1023);
    } else if (q < 2 * XQ) {
      long e = (q - XQ) << 2;
      v = *(const float4*)(h + e);
      dst = Abf + ((long)(e >> 10) * Kn) + INn + (e & 1023);
    } else {
      long e = (q - 2 * XQ) << 2;
      v = *(const float4*)(W + e);
      dst = Wbf + e;
    }
    us4 o;
    o.x = f2bf(v.x); o.y = f2bf(v.y); o.z = f2bf(v.z); o.w = f2bf(v.w);
    *(us4*)dst = o;
  }
}

// ---------- kernel 2: fused GEMM + LSTM epilogue ----------
// 8 waves: wr = wid>>1 (batch 64-group, 0..3), wc = wid&1 (h 32-half).
// Per wave: 64 batch x 128 W-cols = 4 gates x 32 h. Frag n (0..7): gate n&3,
// h-quarter n>>2 -> every lane holds f,i,g,o in-register for its 32 (b,h) cells.
// Bs row s holds W row: gate=(s>>4)&3, h = h0 + (s>>7)*32 + ((s>>6)&1)*16 + (s&15).
// Double-buffer (2 x 64 KB = 128 KB LDS): stage t+1 right after the single per-tile
// barrier -> loads covered by the full ~2500-cyc tile compute; vmcnt(0) drain ~free.
// Buffer race: all waves' reads of buf (t+1)&1 (tile t-1) completed before barrier t
// (lgkmcnt before their consuming MFMAs); sched_barrier pins ordering at each barrier.
// T2 swizzle (HW-verified R5/R8: conflicts == 0): LDS[row][c]=global[row][c^(row&7)]
// via pre-swizzled GLOBAL source + inverse-swizzled ds_read offsets.
#define STAGE_A(t_, b_) do {                                                      \
    const int k0_ = (t_) * BK;                                                    \
    gload16(Ag + (long)(brow + srow      ) * Kn + k0_ + scol, &bufA[b_][(srow      ) * BK + sc8 * 8]); \
    gload16(Ag + (long)(brow + srow + 64 ) * Kn + k0_ + scol, &bufA[b_][(srow + 64 ) * BK + sc8 * 8]); \
    gload16(Ag + (long)(brow + srow + 128) * Kn + k0_ + scol, &bufA[b_][(srow + 128) * BK + sc8 * 8]); \
    gload16(Ag + (long)(brow + srow + 192) * Kn + k0_ + scol, &bufA[b_][(srow + 192) * BK + sc8 * 8]); \
  } while (0)
// grow(srow + i*64) = g0 + i*16 (bits 6,7 of s are the h bits +16/+32)
#define STAGE_B(t_, b_) do {                                                      \
    const int k0_ = (t_) * BK;                                                    \
    gload16(Wg + (long)(g0     ) * Kn + k0_ + scol, &bufB[b_][(srow      ) * BK + sc8 * 8]); \
    gload16(Wg + (long)(g0 + 16) * Kn + k0_ + scol, &bufB[b_][(srow + 64 ) * BK + sc8 * 8]); \
    gload16(Wg + (long)(g0 + 32) * Kn + k0_ + scol, &bufB[b_][(srow + 128) * BK + sc8 * 8]); \
    gload16(Wg + (long)(g0 + 48) * Kn + k0_ + scol, &bufB[b_][(srow + 192) * BK + sc8 * 8]); \
  } while (0)
#define FENCE() do { asm volatile("" ::: "memory"); __builtin_amdgcn_sched_barrier(0); } while (0)

__global__ void __launch_bounds__(512, 2)
lstm_gemm_fused(const unsigned short* __restrict__ Ag,
                const unsigned short* __restrict__ Wg,
                const float* __restrict__ c_prev,
                const float* __restrict__ bias,
                float* __restrict__ out) {
  __shared__ unsigned short bufA[2][BM * BK];   // 2 x 32 KB
  __shared__ unsigned short bufB[2][BN * BK];   // 2 x 32 KB  (total 128 KB)

  const int tid = threadIdx.x;
  const int lane = tid & 63;
  const int wid = tid >> 6;
  const int wr = wid >> 1;            // 0..3 : batch 64-group
  const int wc = wid & 1;             // 0..1 : h 32-half
  const int brow = blockIdx.y * BM;
  const int h0 = blockIdx.x * 64;

  // staging map: 512 thr x 16B = 8 KB per issue-group; 4 issues cover 256 rows
  const int srow = tid >> 3;                      // 0..63
  const int sc8 = tid & 7;                        // dest chunk 0..7
  const int scol = ((sc8 ^ (srow & 7)) * 8);      // pre-swizzled source col (elems)
  const int g0 = ((srow >> 4) & 3) * Hn + h0 + (srow & 15);  // W-row for s=srow

  // fragment read offsets (inverse swizzle): chunk c -> c ^ (row&7), row&7 == l15&7
  const int l15 = lane & 15;
  const int s7 = l15 & 7;
  const int cA = lane >> 4;                       // 0..3
  const int aOff0 = (wr * 64 + l15) * BK + ((cA) ^ s7) * 8;
  const int aOff1 = (wr * 64 + l15) * BK + ((cA + 4) ^ s7) * 8;
  const int bOff0 = (wc * 128 + l15) * BK + ((cA) ^ s7) * 8;
  const int bOff1 = (wc * 128 + l15) * BK + ((cA + 4) ^ s7) * 8;

  f32x4 acc[4][8] = {};   // acc[m][n]: m = batch frag, n = gate(n&3) x h-quarter(n>>2)

  // prologue: stage tile 0 into buf 0 (8 gloads/wave)
  STAGE_A(0, 0); STAGE_B(0, 0);

  for (int t = 0; t < KT; ++t) {
    // boundary: tile t's loads landed (issued a full tile ago, drain ~free)
    asm volatile("s_waitcnt vmcnt(0)" ::: "memory");
    __builtin_amdgcn_s_barrier();
    FENCE();

    // issue-early: stage tile t+1 (covered by the reads+MFMAs below)
    if (t + 1 < KT) {
      const int nb = (t + 1) & 1;
      STAGE_A(t + 1, nb); STAGE_B(t + 1, nb);
    }

    const unsigned short* As = bufA[t & 1];
    const unsigned short* Bs = bufB[t & 1];
    bf16x8 af[4], bfr[8];

    // ---- ks = 0 ----
#pragma unroll
    for (int n = 0; n < 8; ++n) bfr[n] = *(const bf16x8*)&Bs[bOff0 + n * 16 * BK];
#pragma unroll
    for (int m = 0; m < 4; ++m) af[m] = *(const bf16x8*)&As[aOff0 + m * 16 * BK];
    __builtin_amdgcn_s_setprio(1);
#pragma unroll
    for (int m = 0; m < 4; ++m)
#pragma unroll
      for (int n = 0; n < 8; ++n)
        acc[m][n] = __builtin_amdgcn_mfma_f32_16x16x32_bf16(af[m], bfr[n], acc[m][n], 0, 0, 0);
    __builtin_amdgcn_s_setprio(0);

    // ---- ks = 1 ----
#pragma unroll
    for (int n = 0; n < 8; ++n) bfr[n] = *(const bf16x8*)&Bs[bOff1 + n * 16 * BK];
#pragma unroll
    for (int m = 0; m < 4; ++m) af[m] = *(const bf16x8*)&As[aOff1 + m * 16 * BK];
    __builtin_amdgcn_s_setprio(1);
#pragma unroll
    for (int m = 0; m < 4; ++m)
#pragma unroll
      for (int n = 0; n < 8; ++n)
        acc[m][n] = __builtin_amdgcn_mfma_f32_16x16x32_bf16(af[m], bfr[n], acc[m][n], 0, 0, 0);
    __builtin_amdgcn_s_setprio(0);
    FENCE();
  }

  // ---- fused LSTM epilogue, in-register ----
  // C/D (verified m89/m91): col = l15 (h within 16), row = (lane>>4)*4 + j
  const int hq0 = h0 + wc * 32 + l15;       // h for quarter 0 (frags n=0..3)
  const int hq1 = hq0 + 16;                 // h for quarter 1 (frags n=4..7)
  const float bF0 = bias[hq0],        bF1 = bias[hq1];
  const float bI0 = bias[Hn + hq0],   bI1 = bias[Hn + hq1];
  const float bG0 = bias[2*Hn + hq0], bG1 = bias[2*Hn + hq1];
  const float bO0 = bias[3*Hn + hq0], bO1 = bias[3*Hn + hq1];
  const int rbase = brow + wr * 64 + ((lane >> 4) << 2);
  const long BH = (long)Bn * Hn;
#pragma unroll
  for (int m = 0; m < 4; ++m) {
#pragma unroll
    for (int j = 0; j < 4; ++j) {
      const long r = rbase + m * 16 + j;
      {
        const float f = sigm(acc[m][0][j] + bF0);
        const float i_ = sigm(acc[m][1][j] + bI0);
        const float g = tanh_fast(acc[m][2][j] + bG0);
        const float o = sigm(acc[m][3][j] + bO0);
        const float cp = c_prev[r * Hn + hq0];
        const float ct = f * cp + i_ * g;
        out[r * Hn + hq0] = o * tanh_fast(ct);
        out[BH + r * Hn + hq0] = ct;
      }
      {
        const float f = sigm(acc[m][4][j] + bF1);
        const float i_ = sigm(acc[m][5][j] + bI1);
        const float g = tanh_fast(acc[m][6][j] + bG1);
        const float o = sigm(acc[m][7][j] + bO1);
        const float cp = c_prev[r * Hn + hq1];
        const float ct = f * cp + i_ * g;
        out[r * Hn + hq1] = o * tanh_fast(ct);
        out[BH + r * Hn + hq1] = ct;
      }
    }
  }
}

// ---------- launch ----------
extern "C" void kernel_launch(void* const* d_in, const int* in_sizes, int n_in,
                              void* d_out, int out_size, void* d_ws, size_t ws_size,
                              hipStream_t stream) {
  const float* x      = (const float*)d_in[0];
  const float* h_prev = (const float*)d_in[1];
  const float* c_prev = (const float*)d_in[2];
  const float* W      = (const float*)d_in[3];
  const float* bias   = (const float*)d_in[4];
  float* out = (float*)d_out;

  // workspace: A_bf16 (B x K, 16MB) | W_bf16 (4H x K, 16MB)
  unsigned short* Abf = (unsigned short*)d_ws;
  unsigned short* Wbf = Abf + (long)Bn * Kn;

  pack_all<<<2048, 256, 0, stream>>>(x, h_prev, W, Abf, Wbf);

  // grid: x = h tiles (1024/64 = 16), y = batch tiles (4096/256 = 16) -> 256 blocks = 1/CU
  dim3 grid(Hn / 64, Bn / BM);
  lstm_gemm_fused<<<grid, 512, 0, stream>>>(Abf, Wbf, c_prev, bias, out);
}